// Round 10
// baseline (1047.131 us; speedup 1.0000x reference)
//
#include <hip/hip_runtime.h>
#include <hip/hip_bf16.h>
#include <math.h>

#define EMB 512
#define HEADS 16
#define WS 8
#define BSZ 8
#define HW 64
#define NTOK (HW * HW)
#define WN 8
#define M_TOT (BSZ * NTOK)           // 32768
#define NELEM ((size_t)M_TOT * EMB)  // 16,777,216 per activation tensor

typedef _Float16 f16;
typedef _Float16 f16x4 __attribute__((ext_vector_type(4)));
typedef _Float16 f16x8 __attribute__((ext_vector_type(8)));
typedef float f32x4 __attribute__((ext_vector_type(4)));

// ---------------------------------------------------------------------------
// weight conversion. z<4: permute rows to head-major (out row h*32+e comes
// from in row e*16+h) and permute bias; z>=4: identity copy.
// ---------------------------------------------------------------------------
struct CvtW { const float* w[6]; const float* b[4]; f16* out[6]; float* bp; };

__global__ __launch_bounds__(128) void cvt_w(CvtW P) {
  const int z = blockIdx.y;
  const int np = blockIdx.x;                       // output row 0..511
  const int src = (z < 4) ? ((np & 31) * 16 + (np >> 5)) : np;
  const float4* __restrict__ in = (const float4*)(P.w[z] + (size_t)src * 512);
  f16x4* __restrict__ out = (f16x4*)(P.out[z] + (size_t)np * 512);
  const int t = threadIdx.x;                       // 128 threads * 4 cols
  float4 v = in[t];
  f16x4 h = {(f16)v.x, (f16)v.y, (f16)v.z, (f16)v.w};
  out[t] = h;
  if (t == 0 && z < 4) P.bp[z * 512 + np] = P.b[z][src];
}

// ---------------------------------------------------------------------------
// LDS-FREE MFMA GEMM: O[m][n] = sum_k A[m][k]*B[n][k] + bias[n]
// No __shared__, no barriers: each wave loads its MFMA fragments directly
// from global (B is 512 KB -> L2-resident; A re-reads L1-backed: the 4
// wc-waves of a block issue identical A addresses). 8 waves (2 row x 4 col),
// wave tile 64x32 (acc 4x2 -> 32 VGPR), 2-slot named ping-pong prefetch.
// CVT_A: A fp32 held as raw float4, converted at consume time.
// Frag layout identical to the verified LDS version (lane g,c -> row +c,
// k-chunk g*8), so MFMA semantics are unchanged.
// ---------------------------------------------------------------------------
struct GemmF16 { const void* X[4]; const f16* W[4]; const float* Bi[4]; void* O[4]; };

template <bool CVT_A, typename OutT>
__global__ __launch_bounds__(512) void gemm_direct(GemmF16 P) {
  const int z = blockIdx.z;
  const f16* __restrict__ B = P.W[z];
  const float* __restrict__ Bi = P.Bi[z];
  OutT* __restrict__ O = (OutT*)P.O[z];
  const float* __restrict__ A32 = CVT_A ? (const float*)P.X[z] : (const float*)nullptr;
  const f16*  __restrict__ A16 = CVT_A ? (const f16*)nullptr : (const f16*)P.X[z];

  const int tid = threadIdx.x;
  const int lane = tid & 63;
  const int wid = tid >> 6;        // 0..7
  const int wr = wid >> 2;         // 0..1 : row half
  const int wc = wid & 3;          // 0..3 : col quarter
  const int g = lane >> 4;         // 0..3 : k-chunk
  const int c = lane & 15;         // 0..15: row/col within tile
  const size_t m0 = (size_t)blockIdx.x * 128;
  const size_t n0 = (size_t)blockIdx.y * 128;

  size_t aoff[4], boff[2];
  #pragma unroll
  for (int mt = 0; mt < 4; ++mt)
    aoff[mt] = (m0 + wr * 64 + mt * 16 + c) * 512 + g * 8;
  #pragma unroll
  for (int nt = 0; nt < 2; ++nt)
    boff[nt] = ((size_t)n0 + wc * 32 + nt * 16 + c) * 512 + g * 8;

  f32x4 acc[4][2];
  #pragma unroll
  for (int mt = 0; mt < 4; ++mt)
    #pragma unroll
    for (int nt = 0; nt < 2; ++nt) acc[mt][nt] = (f32x4){0.f, 0.f, 0.f, 0.f};

  // two prefetch slots, named (no runtime indexing -> stays in registers)
  float4 alo0[4], ahi0[4], alo1[4], ahi1[4];
  f16x8 a0[4], a1[4], b0[2], b1[2];

#define LOADA(SLOT, K0) do {                                                   \
    _Pragma("unroll")                                                          \
    for (int mt = 0; mt < 4; ++mt) {                                           \
      if (CVT_A) {                                                             \
        const float* p = A32 + aoff[mt] + (K0);                                \
        alo##SLOT[mt] = *(const float4*)p;                                     \
        ahi##SLOT[mt] = *(const float4*)(p + 4);                               \
      } else {                                                                 \
        a##SLOT[mt] = *(const f16x8*)(A16 + aoff[mt] + (K0));                  \
      }                                                                        \
    } } while (0)

#define LOADB(SLOT, K0) do {                                                   \
    _Pragma("unroll")                                                          \
    for (int nt = 0; nt < 2; ++nt)                                             \
      b##SLOT[nt] = *(const f16x8*)(B + boff[nt] + (K0));                      \
  } while (0)

#define COMPUTE(SLOT) do {                                                     \
    f16x8 af[4];                                                               \
    _Pragma("unroll")                                                          \
    for (int mt = 0; mt < 4; ++mt) {                                           \
      if (CVT_A) {                                                             \
        const float4 u = alo##SLOT[mt], v = ahi##SLOT[mt];                     \
        f16x8 hv = {(f16)u.x, (f16)u.y, (f16)u.z, (f16)u.w,                    \
                    (f16)v.x, (f16)v.y, (f16)v.z, (f16)v.w};                   \
        af[mt] = hv;                                                           \
      } else {                                                                 \
        af[mt] = a##SLOT[mt];                                                  \
      }                                                                        \
    }                                                                          \
    _Pragma("unroll")                                                          \
    for (int mt = 0; mt < 4; ++mt)                                             \
      _Pragma("unroll")                                                        \
      for (int nt = 0; nt < 2; ++nt)                                           \
        acc[mt][nt] = __builtin_amdgcn_mfma_f32_16x16x32_f16(                  \
            af[mt], b##SLOT[nt], acc[mt][nt], 0, 0, 0);                        \
  } while (0)

  LOADA(0, 0); LOADB(0, 0);
  #pragma unroll
  for (int t = 0; t < 16; t += 2) {
    if (t + 1 < 16) { LOADA(1, (t + 1) * 32); LOADB(1, (t + 1) * 32); }
    COMPUTE(0);
    if (t + 2 < 16) { LOADA(0, (t + 2) * 32); LOADB(0, (t + 2) * 32); }
    if (t + 1 < 16) COMPUTE(1);
  }
#undef LOADA
#undef LOADB
#undef COMPUTE

  // epilogue: D col = lane&15, row = (lane>>4)*4 + r  [m89-verified layout]
  const int col_base = (int)n0 + wc * 32;
  const int row_base = (int)m0 + wr * 64 + g * 4;
  float bv[2];
  #pragma unroll
  for (int nt = 0; nt < 2; ++nt) bv[nt] = Bi[col_base + nt * 16 + c];
  #pragma unroll
  for (int mt = 0; mt < 4; ++mt)
    #pragma unroll
    for (int nt = 0; nt < 2; ++nt)
      #pragma unroll
      for (int r = 0; r < 4; ++r) {
        const size_t row = (size_t)(row_base + mt * 16 + r);
        O[row * 512 + col_base + nt * 16 + c] = (OutT)(acc[mt][nt][r] + bv[nt]);
      }
}

// ---------------------------------------------------------------------------
// MFMA windowed attention. One WAVE per (b,h,wi,wj); 4 waves/block.
// (unchanged from round 6 -- verified correct & fast)
// ---------------------------------------------------------------------------
__global__ __launch_bounds__(256) void attn_kernel(
    const f16* __restrict__ cq, const f16* __restrict__ ck,
    const f16* __restrict__ vs, const f16* __restrict__ vh,
    const float* __restrict__ pe, f16* __restrict__ osc, f16* __restrict__ osh) {
  __shared__ f16 Pl[4][64][72];     // per-wave P[q][kv], stride 144B (16B mult)
  __shared__ float pesh[228];

  const int tid = threadIdx.x;
  for (int i = tid; i < 225; i += 256) pesh[i] = pe[i];
  __syncthreads();                  // only barrier (pesh shared per block)

  const int wid = tid >> 6;
  const int lane = tid & 63;
  const int g = lane >> 4;          // 0..3
  const int c = lane & 15;          // 0..15
  const int w = blockIdx.x * 4 + wid;
  const int wj = w & 7;
  const int wi = (w >> 3) & 7;
  const int h  = (w >> 6) & 15;
  const int b  = w >> 10;

  size_t taddr[4];
  #pragma unroll
  for (int i = 0; i < 4; ++i) {
    const int ty = (wi * 8 + i * 2 + (c >> 3) + 4) & 63;
    const int tx = (wj * 8 + (c & 7) + 4) & 63;
    taddr[i] = ((size_t)b * NTOK + ty * 64 + tx) * EMB + h * 32 + g * 8;
  }
  f16x8 kf[4], qf[4];
  #pragma unroll
  for (int i = 0; i < 4; ++i) {
    kf[i] = *(const f16x8*)(ck + taddr[i]);
    qf[i] = *(const f16x8*)(cq + taddr[i]);
  }

  f32x4 s[4][4];
  #pragma unroll
  for (int mt = 0; mt < 4; ++mt)
    #pragma unroll
    for (int kt = 0; kt < 4; ++kt) s[mt][kt] = (f32x4){0.f, 0.f, 0.f, 0.f};
  #pragma unroll
  for (int mt = 0; mt < 4; ++mt)
    #pragma unroll
    for (int kt = 0; kt < 4; ++kt)
      s[mt][kt] = __builtin_amdgcn_mfma_f32_16x16x32_f16(kf[mt], qf[kt],
                                                         s[mt][kt], 0, 0, 0);

  const float invs = 0.17677669529663687f;  // 1/sqrt(32)
  const bool rm = (wi == 7);
  const bool cm = (wj == 7) && (((c >> 2) & 1) != (g & 1));  // lane-constant
  #pragma unroll
  for (int mt = 0; mt < 4; ++mt)
    #pragma unroll
    for (int kt = 0; kt < 4; ++kt) {
      const bool rmask = rm && ((mt >> 1) != (kt >> 1));     // acc-uniform
      const int ry = (mt - kt) * 2 + (g >> 1) - (c >> 3) + 7;
      #pragma unroll
      for (int r = 0; r < 4; ++r) {
        const int rx = (g & 1) * 4 + r - (c & 7) + 7;
        float d = s[mt][kt][r] * invs + pesh[ry * 15 + rx];
        if (rmask || cm) d = -1e30f;
        s[mt][kt][r] = d;
      }
    }

  #pragma unroll
  for (int kt = 0; kt < 4; ++kt) {
    float m = -1e30f;
    #pragma unroll
    for (int mt = 0; mt < 4; ++mt)
      #pragma unroll
      for (int r = 0; r < 4; ++r) m = fmaxf(m, s[mt][kt][r]);
    m = fmaxf(m, __shfl_xor(m, 16));
    m = fmaxf(m, __shfl_xor(m, 32));
    float sum = 0.f;
    #pragma unroll
    for (int mt = 0; mt < 4; ++mt)
      #pragma unroll
      for (int r = 0; r < 4; ++r) {
        const float p = __expf(s[mt][kt][r] - m);
        s[mt][kt][r] = p;
        sum += p;
      }
    sum += __shfl_xor(sum, 16);
    sum += __shfl_xor(sum, 32);
    const float rs = 1.f / sum;
    #pragma unroll
    for (int mt = 0; mt < 4; ++mt)
      #pragma unroll
      for (int r = 0; r < 4; ++r) s[mt][kt][r] *= rs;
  }

  #pragma unroll
  for (int mt = 0; mt < 4; ++mt)
    #pragma unroll
    for (int kt = 0; kt < 4; ++kt) {
      f16x4 pk = {(f16)s[mt][kt][0], (f16)s[mt][kt][1],
                  (f16)s[mt][kt][2], (f16)s[mt][kt][3]};
      *(f16x4*)&Pl[wid][kt * 16 + c][mt * 16 + g * 4] = pk;
    }

  size_t vb[2];
  #pragma unroll
  for (int ks = 0; ks < 2; ++ks) {
    const int vy = (wi * 8 + ks * 4 + g + 4) & 63;
    vb[ks] = ((size_t)b * NTOK + vy * 64) * EMB + h * 32 + c;
  }
  int xo[8];
  #pragma unroll
  for (int j = 0; j < 8; ++j) xo[j] = ((wj * 8 + j + 4) & 63) * EMB;

  f16x8 vfs[2][2], vfh[2][2];   // [nt][ks]
  #pragma unroll
  for (int nt = 0; nt < 2; ++nt)
    #pragma unroll
    for (int ks = 0; ks < 2; ++ks)
      #pragma unroll
      for (int j = 0; j < 8; ++j) {
        const size_t a = vb[ks] + xo[j] + nt * 16;
        vfs[nt][ks][j] = vs[a];
        vfh[nt][ks][j] = vh[a];
      }

  f16x8 af[4][2];
  #pragma unroll
  for (int mt = 0; mt < 4; ++mt)
    #pragma unroll
    for (int ks = 0; ks < 2; ++ks)
      af[mt][ks] = *(const f16x8*)&Pl[wid][mt * 16 + c][ks * 32 + g * 8];

  size_t ob[4];
  #pragma unroll
  for (int mt = 0; mt < 4; ++mt) {
    const int np = (wi * 8 + 2 * mt + (g >> 1)) * 64 + wj * 8 + 4 * (g & 1);
    ob[mt] = ((size_t)b * NTOK + np) * EMB + h * 32 + c;
  }

  {
    f32x4 o[4][2];
    #pragma unroll
    for (int mt = 0; mt < 4; ++mt)
      #pragma unroll
      for (int nt = 0; nt < 2; ++nt) o[mt][nt] = (f32x4){0.f, 0.f, 0.f, 0.f};
    #pragma unroll
    for (int mt = 0; mt < 4; ++mt)
      #pragma unroll
      for (int nt = 0; nt < 2; ++nt)
        #pragma unroll
        for (int ks = 0; ks < 2; ++ks)
          o[mt][nt] = __builtin_amdgcn_mfma_f32_16x16x32_f16(
              af[mt][ks], vfs[nt][ks], o[mt][nt], 0, 0, 0);
    #pragma unroll
    for (int mt = 0; mt < 4; ++mt)
      #pragma unroll
      for (int nt = 0; nt < 2; ++nt)
        #pragma unroll
        for (int r = 0; r < 4; ++r)
          osc[ob[mt] + (size_t)r * EMB + nt * 16] = (f16)o[mt][nt][r];
  }
  {
    f32x4 o[4][2];
    #pragma unroll
    for (int mt = 0; mt < 4; ++mt)
      #pragma unroll
      for (int nt = 0; nt < 2; ++nt) o[mt][nt] = (f32x4){0.f, 0.f, 0.f, 0.f};
    #pragma unroll
    for (int mt = 0; mt < 4; ++mt)
      #pragma unroll
      for (int nt = 0; nt < 2; ++nt)
        #pragma unroll
        for (int ks = 0; ks < 2; ++ks)
          o[mt][nt] = __builtin_amdgcn_mfma_f32_16x16x32_f16(
              af[mt][ks], vfh[nt][ks], o[mt][nt], 0, 0, 0);
    #pragma unroll
    for (int mt = 0; mt < 4; ++mt)
      #pragma unroll
      for (int nt = 0; nt < 2; ++nt)
        #pragma unroll
        for (int r = 0; r < 4; ++r)
          osh[ob[mt] + (size_t)r * EMB + nt * 16] = (f16)o[mt][nt][r];
  }
}

// ---------------------------------------------------------------------------
extern "C" void kernel_launch(void* const* d_in, const int* in_sizes, int n_in,
                              void* d_out, int out_size, void* d_ws, size_t ws_size,
                              hipStream_t stream) {
  const float* content = (const float*)d_in[0];
  const float* style   = (const float*)d_in[1];
  const float* scalex  = (const float*)d_in[2];
  const float* shiftx  = (const float*)d_in[3];
  const float* W1  = (const float*)d_in[4];  const float* b1  = (const float*)d_in[5];
  const float* W2  = (const float*)d_in[6];  const float* b2  = (const float*)d_in[7];
  const float* Wsc = (const float*)d_in[8];  const float* bsc = (const float*)d_in[9];
  const float* Wsh = (const float*)d_in[10]; const float* bsh = (const float*)d_in[11];
  const float* Wso = (const float*)d_in[12]; const float* bso = (const float*)d_in[13];
  const float* Wsho= (const float*)d_in[14]; const float* bsho= (const float*)d_in[15];
  const float* pos = (const float*)d_in[16];
  float* out = (float*)d_out;

  // workspace: Wh(6x262144 f16) | bp(2048 f32) | Ph(4xNELEM f16) | Oh(2xNELEM f16)
  f16* Wh = (f16*)d_ws;
  float* bp = (float*)(Wh + 6 * 262144);
  f16* Ph = (f16*)(bp + 2048);
  f16* Oh = Ph + 4 * NELEM;

  // 1) convert weights (P1 rows permuted to head-major) + biases
  CvtW CW;
  CW.w[0] = W1; CW.w[1] = W2; CW.w[2] = Wsc; CW.w[3] = Wsh; CW.w[4] = Wso; CW.w[5] = Wsho;
  CW.b[0] = b1; CW.b[1] = b2; CW.b[2] = bsc; CW.b[3] = bsh;
  for (int i = 0; i < 6; ++i) CW.out[i] = Wh + (size_t)i * 262144;
  CW.bp = bp;
  hipLaunchKernelGGL(cvt_w, dim3(512, 6), dim3(128), 0, stream, CW);

  // 2) input projections: fp32 A converted at consume, f16 head-major out
  GemmF16 P1;
  P1.X[0] = content; P1.X[1] = style; P1.X[2] = scalex; P1.X[3] = shiftx;
  for (int i = 0; i < 4; ++i) {
    P1.W[i] = Wh + (size_t)i * 262144;
    P1.Bi[i] = bp + i * 512;
    P1.O[i] = Ph + (size_t)i * NELEM;
  }
  hipLaunchKernelGGL(HIP_KERNEL_NAME(gemm_direct<true, f16>),
                     dim3(M_TOT / 128, EMB / 128, 4), dim3(512), 0, stream, P1);

  // 3) attention: 8192 window-heads, 1 wave each, 4 waves/block
  hipLaunchKernelGGL(attn_kernel, dim3(BSZ * HEADS * WN * WN / 4), dim3(256), 0,
                     stream, Ph, Ph + NELEM, Ph + 2 * NELEM, Ph + 3 * NELEM, pos,
                     Oh, Oh + NELEM);

  // 4) output projections (f16 A, fp32 out -> d_out)
  GemmF16 P2;
  P2.X[0] = Oh;          P2.W[0] = Wh + 4 * 262144; P2.Bi[0] = bso;  P2.O[0] = out;
  P2.X[1] = Oh + NELEM;  P2.W[1] = Wh + 5 * 262144; P2.Bi[1] = bsho; P2.O[1] = out + NELEM;
  P2.X[2] = P2.X[0]; P2.W[2] = P2.W[0]; P2.Bi[2] = P2.Bi[0]; P2.O[2] = P2.O[0];
  P2.X[3] = P2.X[1]; P2.W[3] = P2.W[1]; P2.Bi[3] = P2.Bi[1]; P2.O[3] = P2.O[1];
  hipLaunchKernelGGL(HIP_KERNEL_NAME(gemm_direct<false, float>),
                     dim3(M_TOT / 128, EMB / 128, 2), dim3(512), 0, stream, P2);
}

// Round 11
// 538.428 us; speedup vs baseline: 1.9448x; 1.9448x over previous
//
#include <hip/hip_runtime.h>
#include <hip/hip_bf16.h>
#include <math.h>

#define EMB 512
#define HEADS 16
#define WS 8
#define BSZ 8
#define HW 64
#define NTOK (HW * HW)
#define WN 8
#define M_TOT (BSZ * NTOK)           // 32768
#define NELEM ((size_t)M_TOT * EMB)  // 16,777,216 per activation tensor

typedef _Float16 f16;
typedef _Float16 f16x4 __attribute__((ext_vector_type(4)));
typedef _Float16 f16x8 __attribute__((ext_vector_type(8)));
typedef float f32x4 __attribute__((ext_vector_type(4)));

// counted-vmcnt barrier: keep N vector-mem ops in flight across the barrier
#define BAR(N_STR) asm volatile("s_waitcnt vmcnt(" N_STR ") lgkmcnt(0)\n\ts_barrier" ::: "memory")

// ---------------------------------------------------------------------------
// weight conversion. z<4: permute rows to head-major (out row h*32+e comes
// from in row e*16+h) and permute bias; z>=4: identity copy.
// ---------------------------------------------------------------------------
struct CvtW { const float* w[6]; const float* b[4]; f16* out[6]; float* bp; };

__global__ __launch_bounds__(128) void cvt_w(CvtW P) {
  const int z = blockIdx.y;
  const int np = blockIdx.x;                       // output row 0..511
  const int src = (z < 4) ? ((np & 31) * 16 + (np >> 5)) : np;
  const float4* __restrict__ in = (const float4*)(P.w[z] + (size_t)src * 512);
  f16x4* __restrict__ out = (f16x4*)(P.out[z] + (size_t)np * 512);
  const int t = threadIdx.x;                       // 128 threads * 4 cols
  float4 v = in[t];
  f16x4 h = {(f16)v.x, (f16)v.y, (f16)v.z, (f16)v.w};
  out[t] = h;
  if (t == 0 && z < 4) P.bp[z * 512 + np] = P.b[z][src];
}

// ---------------------------------------------------------------------------
// f16 MFMA GEMM, 3-buffer counted-vmcnt pipeline (T3/T4):
// 128x128 tile, BK=32, 4 waves (2x2), 16x16x32 MFMA. Stage 2 K-tiles ahead;
// per-step barrier = s_waitcnt vmcnt(6|4) lgkmcnt(0); s_barrier -- tile t+2's
// loads stay in flight, tile t+1's are drained by the count. CVT_A: A fp32
// reg-staged (2 named sets, cvt at write); else A via global_load_lds like B.
// LDS slot swizzle slot' = q ^ ((row>>1)&3), matched on stage & read
// (verified rounds 5/6).
// ---------------------------------------------------------------------------
struct GemmF16 { const void* X[4]; const f16* W[4]; const float* Bi[4]; void* O[4]; };

template <bool CVT_A, typename OutT>
__global__ __launch_bounds__(256) void gemm_pipe(GemmF16 P) {
  const int z = blockIdx.z;
  const f16* __restrict__ B = P.W[z];
  const float* __restrict__ Bi = P.Bi[z];
  OutT* __restrict__ O = (OutT*)P.O[z];

  __shared__ f16 lds[3][2][128 * 32];   // [buf][A/B][row*32+col], 48 KiB

  const int tid = threadIdx.x;
  const int lane = tid & 63;
  const int wid = tid >> 6;
  const int wr = wid >> 1, wc = wid & 1;
  const size_t m0 = (size_t)blockIdx.x * 128;
  const size_t n0 = (size_t)blockIdx.y * 128;

  const f16*  Ag16 = CVT_A ? (const f16*)nullptr : ((const f16*)P.X[z] + m0 * 512);
  const float* Ag32 = CVT_A ? ((const float*)P.X[z] + m0 * 512) : (const float*)nullptr;
  const f16* Bg = B + n0 * 512;

  // staging decomposition: lane -> (row-in-16 rl, k-chunk); inverse-swizzled src
  const int rl = lane >> 2;
  const int qs = (lane & 3) ^ ((rl >> 1) & 3);
  const size_t goff16 = (size_t)rl * 512 + (size_t)qs * 8;

  const int c = lane & 15;
  const int g = lane >> 4;

  // fragment ds_read offsets (f16 units), swizzled
  int aoff[4], boff[4];
  #pragma unroll
  for (int i = 0; i < 4; ++i) {
    const int rowa = wr * 64 + i * 16 + c;
    aoff[i] = rowa * 32 + ((g ^ ((rowa >> 1) & 3)) * 8);
    const int rowb = wc * 64 + i * 16 + c;
    boff[i] = rowb * 32 + ((g ^ ((rowb >> 1) & 3)) * 8);
  }

  f32x4 acc[4][4];
  #pragma unroll
  for (int i = 0; i < 4; ++i)
    #pragma unroll
    for (int j = 0; j < 4; ++j) acc[i][j] = (f32x4){0.f, 0.f, 0.f, 0.f};

  // two named A-reg sets (CVT_A): set = tile%2
  float4 alo0[2][2], alo1[2][2];   // [ii][half]

#define LOAD_A32(SET, k0) do { if (CVT_A) {                                    \
    _Pragma("unroll")                                                          \
    for (int ii = 0; ii < 2; ++ii) {                                           \
      const int s = wid * 2 + ii;                                              \
      const float* ga = Ag32 + (size_t)(s * 16 + rl) * 512 + (size_t)(k0)      \
                        + (size_t)qs * 8;                                      \
      alo##SET[ii][0] = *(const float4*)ga;                                    \
      alo##SET[ii][1] = *(const float4*)(ga + 4);                              \
    } } } while (0)

#define WRITE_A(SET, buf) do { if (CVT_A) {                                    \
    _Pragma("unroll")                                                          \
    for (int ii = 0; ii < 2; ++ii) {                                           \
      const int s = wid * 2 + ii;                                              \
      const float* ap = (const float*)&alo##SET[ii][0];                        \
      f16x8 hv;                                                                \
      _Pragma("unroll")                                                        \
      for (int j = 0; j < 8; ++j) hv[j] = (f16)ap[j];                          \
      *(f16x8*)&lds[buf][0][(size_t)s * 512 + (size_t)lane * 8] = hv;          \
    } } } while (0)

#define STAGE_A16(buf, k0) do { if (!CVT_A) {                                  \
    _Pragma("unroll")                                                          \
    for (int ii = 0; ii < 2; ++ii) {                                           \
      const int s = wid * 2 + ii;                                              \
      const f16* ga = Ag16 + (size_t)s * 16 * 512 + (size_t)(k0) + goff16;     \
      __builtin_amdgcn_global_load_lds(                                        \
          (const __attribute__((address_space(1))) void*)ga,                   \
          (__attribute__((address_space(3))) void*)&lds[buf][0][s * 512],      \
          16, 0, 0);                                                           \
    } } } while (0)

#define STAGE_B(buf, k0) do {                                                  \
    _Pragma("unroll")                                                          \
    for (int ii = 0; ii < 2; ++ii) {                                           \
      const int s = wid * 2 + ii;                                              \
      const f16* gb = Bg + (size_t)s * 16 * 512 + (size_t)(k0) + goff16;       \
      __builtin_amdgcn_global_load_lds(                                        \
          (const __attribute__((address_space(1))) void*)gb,                   \
          (__attribute__((address_space(3))) void*)&lds[buf][1][s * 512],      \
          16, 0, 0);                                                           \
    } } while (0)

  // ---- prologue: tiles 0 and 1 ----
  if (CVT_A) {
    LOAD_A32(0, 0);  STAGE_B(0, 0);
    LOAD_A32(1, 32); STAGE_B(1, 32);
    WRITE_A(0, 0);              // compiler waits A0 regs; B0,A1,B1 in flight
    BAR("6");                   // drain B0; keep A1(4)+B1(2)
  } else {
    STAGE_A16(0, 0);  STAGE_B(0, 0);
    STAGE_A16(1, 32); STAGE_B(1, 32);
    BAR("4");                   // drain tile0's 4; keep tile1's 4
  }

  // ---- main loop: fully unrolled so %3/%2 fold to immediates ----
  #pragma unroll
  for (int t = 0; t < 16; ++t) {
    const int cur = t % 3;
    if (t + 2 < 16) {
      if (CVT_A) {
        if (((t + 2) & 1) == 0) LOAD_A32(0, (t + 2) * 32);
        else                    LOAD_A32(1, (t + 2) * 32);
      } else {
        STAGE_A16((t + 2) % 3, (t + 2) * 32);
      }
      STAGE_B((t + 2) % 3, (t + 2) * 32);
    }

    f16x8 af[4], bf[4];
    #pragma unroll
    for (int i = 0; i < 4; ++i) {
      af[i] = *(const f16x8*)&lds[cur][0][aoff[i]];
      bf[i] = *(const f16x8*)&lds[cur][1][boff[i]];
    }
    #pragma unroll
    for (int mi = 0; mi < 4; ++mi)
      #pragma unroll
      for (int ni = 0; ni < 4; ++ni)
        acc[mi][ni] = __builtin_amdgcn_mfma_f32_16x16x32_f16(
            af[mi], bf[ni], acc[mi][ni], 0, 0, 0);

    if (CVT_A && t + 1 < 16) {
      if (((t + 1) & 1) == 0) WRITE_A(0, (t + 1) % 3);
      else                    WRITE_A(1, (t + 1) % 3);
    }

    if (t < 14) {
      if (CVT_A) BAR("6");      // drain B(t+1); keep A(t+2)4 + B(t+2)2
      else       BAR("4");      // drain tile t+1's 4; keep tile t+2's 4
    } else if (t == 14) {
      BAR("0");                 // tail: tile 15 must be fully resident
    }
  }
#undef LOAD_A32
#undef WRITE_A
#undef STAGE_A16
#undef STAGE_B

  // epilogue: D col = lane&15, row = (lane>>4)*4 + r  [m89-verified layout]
  const int col_base = (int)n0 + wc * 64;
  const int row_base = (int)m0 + wr * 64 + g * 4;
  float bv[4];
  #pragma unroll
  for (int ni = 0; ni < 4; ++ni) bv[ni] = Bi[col_base + ni * 16 + c];
  #pragma unroll
  for (int mi = 0; mi < 4; ++mi)
    #pragma unroll
    for (int ni = 0; ni < 4; ++ni)
      #pragma unroll
      for (int r = 0; r < 4; ++r) {
        const size_t row = (size_t)(row_base + mi * 16 + r);
        O[row * 512 + col_base + ni * 16 + c] = (OutT)(acc[mi][ni][r] + bv[ni]);
      }
}

// ---------------------------------------------------------------------------
// MFMA windowed attention. One WAVE per (b,h,wi,wj); 4 waves/block.
// (unchanged from round 6 -- verified correct & fast)
// ---------------------------------------------------------------------------
__global__ __launch_bounds__(256) void attn_kernel(
    const f16* __restrict__ cq, const f16* __restrict__ ck,
    const f16* __restrict__ vs, const f16* __restrict__ vh,
    const float* __restrict__ pe, f16* __restrict__ osc, f16* __restrict__ osh) {
  __shared__ f16 Pl[4][64][72];     // per-wave P[q][kv], stride 144B (16B mult)
  __shared__ float pesh[228];

  const int tid = threadIdx.x;
  for (int i = tid; i < 225; i += 256) pesh[i] = pe[i];
  __syncthreads();                  // only barrier (pesh shared per block)

  const int wid = tid >> 6;
  const int lane = tid & 63;
  const int g = lane >> 4;          // 0..3
  const int c = lane & 15;          // 0..15
  const int w = blockIdx.x * 4 + wid;
  const int wj = w & 7;
  const int wi = (w >> 3) & 7;
  const int h  = (w >> 6) & 15;
  const int b  = w >> 10;

  size_t taddr[4];
  #pragma unroll
  for (int i = 0; i < 4; ++i) {
    const int ty = (wi * 8 + i * 2 + (c >> 3) + 4) & 63;
    const int tx = (wj * 8 + (c & 7) + 4) & 63;
    taddr[i] = ((size_t)b * NTOK + ty * 64 + tx) * EMB + h * 32 + g * 8;
  }
  f16x8 kf[4], qf[4];
  #pragma unroll
  for (int i = 0; i < 4; ++i) {
    kf[i] = *(const f16x8*)(ck + taddr[i]);
    qf[i] = *(const f16x8*)(cq + taddr[i]);
  }

  f32x4 s[4][4];
  #pragma unroll
  for (int mt = 0; mt < 4; ++mt)
    #pragma unroll
    for (int kt = 0; kt < 4; ++kt) s[mt][kt] = (f32x4){0.f, 0.f, 0.f, 0.f};
  #pragma unroll
  for (int mt = 0; mt < 4; ++mt)
    #pragma unroll
    for (int kt = 0; kt < 4; ++kt)
      s[mt][kt] = __builtin_amdgcn_mfma_f32_16x16x32_f16(kf[mt], qf[kt],
                                                         s[mt][kt], 0, 0, 0);

  const float invs = 0.17677669529663687f;  // 1/sqrt(32)
  const bool rm = (wi == 7);
  const bool cm = (wj == 7) && (((c >> 2) & 1) != (g & 1));  // lane-constant
  #pragma unroll
  for (int mt = 0; mt < 4; ++mt)
    #pragma unroll
    for (int kt = 0; kt < 4; ++kt) {
      const bool rmask = rm && ((mt >> 1) != (kt >> 1));     // acc-uniform
      const int ry = (mt - kt) * 2 + (g >> 1) - (c >> 3) + 7;
      #pragma unroll
      for (int r = 0; r < 4; ++r) {
        const int rx = (g & 1) * 4 + r - (c & 7) + 7;
        float d = s[mt][kt][r] * invs + pesh[ry * 15 + rx];
        if (rmask || cm) d = -1e30f;
        s[mt][kt][r] = d;
      }
    }

  #pragma unroll
  for (int kt = 0; kt < 4; ++kt) {
    float m = -1e30f;
    #pragma unroll
    for (int mt = 0; mt < 4; ++mt)
      #pragma unroll
      for (int r = 0; r < 4; ++r) m = fmaxf(m, s[mt][kt][r]);
    m = fmaxf(m, __shfl_xor(m, 16));
    m = fmaxf(m, __shfl_xor(m, 32));
    float sum = 0.f;
    #pragma unroll
    for (int mt = 0; mt < 4; ++mt)
      #pragma unroll
      for (int r = 0; r < 4; ++r) {
        const float p = __expf(s[mt][kt][r] - m);
        s[mt][kt][r] = p;
        sum += p;
      }
    sum += __shfl_xor(sum, 16);
    sum += __shfl_xor(sum, 32);
    const float rs = 1.f / sum;
    #pragma unroll
    for (int mt = 0; mt < 4; ++mt)
      #pragma unroll
      for (int r = 0; r < 4; ++r) s[mt][kt][r] *= rs;
  }

  #pragma unroll
  for (int mt = 0; mt < 4; ++mt)
    #pragma unroll
    for (int kt = 0; kt < 4; ++kt) {
      f16x4 pk = {(f16)s[mt][kt][0], (f16)s[mt][kt][1],
                  (f16)s[mt][kt][2], (f16)s[mt][kt][3]};
      *(f16x4*)&Pl[wid][kt * 16 + c][mt * 16 + g * 4] = pk;
    }

  size_t vb[2];
  #pragma unroll
  for (int ks = 0; ks < 2; ++ks) {
    const int vy = (wi * 8 + ks * 4 + g + 4) & 63;
    vb[ks] = ((size_t)b * NTOK + vy * 64) * EMB + h * 32 + c;
  }
  int xo[8];
  #pragma unroll
  for (int j = 0; j < 8; ++j) xo[j] = ((wj * 8 + j + 4) & 63) * EMB;

  f16x8 vfs[2][2], vfh[2][2];   // [nt][ks]
  #pragma unroll
  for (int nt = 0; nt < 2; ++nt)
    #pragma unroll
    for (int ks = 0; ks < 2; ++ks)
      #pragma unroll
      for (int j = 0; j < 8; ++j) {
        const size_t a = vb[ks] + xo[j] + nt * 16;
        vfs[nt][ks][j] = vs[a];
        vfh[nt][ks][j] = vh[a];
      }

  f16x8 af[4][2];
  #pragma unroll
  for (int mt = 0; mt < 4; ++mt)
    #pragma unroll
    for (int ks = 0; ks < 2; ++ks)
      af[mt][ks] = *(const f16x8*)&Pl[wid][mt * 16 + c][ks * 32 + g * 8];

  size_t ob[4];
  #pragma unroll
  for (int mt = 0; mt < 4; ++mt) {
    const int np = (wi * 8 + 2 * mt + (g >> 1)) * 64 + wj * 8 + 4 * (g & 1);
    ob[mt] = ((size_t)b * NTOK + np) * EMB + h * 32 + c;
  }

  {
    f32x4 o[4][2];
    #pragma unroll
    for (int mt = 0; mt < 4; ++mt)
      #pragma unroll
      for (int nt = 0; nt < 2; ++nt) o[mt][nt] = (f32x4){0.f, 0.f, 0.f, 0.f};
    #pragma unroll
    for (int mt = 0; mt < 4; ++mt)
      #pragma unroll
      for (int nt = 0; nt < 2; ++nt)
        #pragma unroll
        for (int ks = 0; ks < 2; ++ks)
          o[mt][nt] = __builtin_amdgcn_mfma_f32_16x16x32_f16(
              af[mt][ks], vfs[nt][ks], o[mt][nt], 0, 0, 0);
    #pragma unroll
    for (int mt = 0; mt < 4; ++mt)
      #pragma unroll
      for (int nt = 0; nt < 2; ++nt)
        #pragma unroll
        for (int r = 0; r < 4; ++r)
          osc[ob[mt] + (size_t)r * EMB + nt * 16] = (f16)o[mt][nt][r];
  }
  {
    f32x4 o[4][2];
    #pragma unroll
    for (int mt = 0; mt < 4; ++mt)
      #pragma unroll
      for (int nt = 0; nt < 2; ++nt) o[mt][nt] = (f32x4){0.f, 0.f, 0.f, 0.f};
    #pragma unroll
    for (int mt = 0; mt < 4; ++mt)
      #pragma unroll
      for (int nt = 0; nt < 2; ++nt)
        #pragma unroll
        for (int ks = 0; ks < 2; ++ks)
          o[mt][nt] = __builtin_amdgcn_mfma_f32_16x16x32_f16(
              af[mt][ks], vfh[nt][ks], o[mt][nt], 0, 0, 0);
    #pragma unroll
    for (int mt = 0; mt < 4; ++mt)
      #pragma unroll
      for (int nt = 0; nt < 2; ++nt)
        #pragma unroll
        for (int r = 0; r < 4; ++r)
          osh[ob[mt] + (size_t)r * EMB + nt * 16] = (f16)o[mt][nt][r];
  }
}

// ---------------------------------------------------------------------------
extern "C" void kernel_launch(void* const* d_in, const int* in_sizes, int n_in,
                              void* d_out, int out_size, void* d_ws, size_t ws_size,
                              hipStream_t stream) {
  const float* content = (const float*)d_in[0];
  const float* style   = (const float*)d_in[1];
  const float* scalex  = (const float*)d_in[2];
  const float* shiftx  = (const float*)d_in[3];
  const float* W1  = (const float*)d_in[4];  const float* b1  = (const float*)d_in[5];
  const float* W2  = (const float*)d_in[6];  const float* b2  = (const float*)d_in[7];
  const float* Wsc = (const float*)d_in[8];  const float* bsc = (const float*)d_in[9];
  const float* Wsh = (const float*)d_in[10]; const float* bsh = (const float*)d_in[11];
  const float* Wso = (const float*)d_in[12]; const float* bso = (const float*)d_in[13];
  const float* Wsho= (const float*)d_in[14]; const float* bsho= (const float*)d_in[15];
  const float* pos = (const float*)d_in[16];
  float* out = (float*)d_out;

  // workspace: Wh(6x262144 f16) | bp(2048 f32) | Ph(4xNELEM f16) | Oh(2xNELEM f16)
  f16* Wh = (f16*)d_ws;
  float* bp = (float*)(Wh + 6 * 262144);
  f16* Ph = (f16*)(bp + 2048);
  f16* Oh = Ph + 4 * NELEM;

  // 1) convert weights (P1 rows permuted to head-major) + biases
  CvtW CW;
  CW.w[0] = W1; CW.w[1] = W2; CW.w[2] = Wsc; CW.w[3] = Wsh; CW.w[4] = Wso; CW.w[5] = Wsho;
  CW.b[0] = b1; CW.b[1] = b2; CW.b[2] = bsc; CW.b[3] = bsh;
  for (int i = 0; i < 6; ++i) CW.out[i] = Wh + (size_t)i * 262144;
  CW.bp = bp;
  hipLaunchKernelGGL(cvt_w, dim3(512, 6), dim3(128), 0, stream, CW);

  // 2) input projections: fp32 A converted in-staging, f16 head-major out
  GemmF16 P1;
  P1.X[0] = content; P1.X[1] = style; P1.X[2] = scalex; P1.X[3] = shiftx;
  for (int i = 0; i < 4; ++i) {
    P1.W[i] = Wh + (size_t)i * 262144;
    P1.Bi[i] = bp + i * 512;
    P1.O[i] = Ph + (size_t)i * NELEM;
  }
  hipLaunchKernelGGL(HIP_KERNEL_NAME(gemm_pipe<true, f16>),
                     dim3(M_TOT / 128, EMB / 128, 4), dim3(256), 0, stream, P1);

  // 3) attention: 8192 window-heads, 1 wave each, 4 waves/block
  hipLaunchKernelGGL(attn_kernel, dim3(BSZ * HEADS * WN * WN / 4), dim3(256), 0,
                     stream, Ph, Ph + NELEM, Ph + 2 * NELEM, Ph + 3 * NELEM, pos,
                     Oh, Oh + NELEM);

  // 4) output projections (f16 A via global_load_lds, fp32 out -> d_out)
  GemmF16 P2;
  P2.X[0] = Oh;          P2.W[0] = Wh + 4 * 262144; P2.Bi[0] = bso;  P2.O[0] = out;
  P2.X[1] = Oh + NELEM;  P2.W[1] = Wh + 5 * 262144; P2.Bi[1] = bsho; P2.O[1] = out + NELEM;
  P2.X[2] = P2.X[0]; P2.W[2] = P2.W[0]; P2.Bi[2] = P2.Bi[0]; P2.O[2] = P2.O[0];
  P2.X[3] = P2.X[1]; P2.W[3] = P2.W[1]; P2.Bi[3] = P2.Bi[1]; P2.O[3] = P2.O[1];
  hipLaunchKernelGGL(HIP_KERNEL_NAME(gemm_pipe<false, float>),
                     dim3(M_TOT / 128, EMB / 128, 2), dim3(256), 0, stream, P2);
}